// Round 2
// 284.677 us; speedup vs baseline: 1.0298x; 1.0298x over previous
//
#include <hip/hip_runtime.h>

#define Bdim 8
#define Tdim 100
#define Sdim 400
#define Kk   8
#define Hdim 512
#define Vdim 32000
#define Mdim 800          // B*T
#define VHALF 16000

typedef __attribute__((ext_vector_type(8))) short short8;     // 8 bf16 = 4 VGPRs
typedef __attribute__((ext_vector_type(4))) short short4v;    // 4 bf16 = 2 VGPRs
typedef __attribute__((ext_vector_type(4))) float float4_t;   // MFMA acc

static __device__ __forceinline__ unsigned short f2bf(float f) {
    unsigned int x = __float_as_uint(f);
    return (unsigned short)((x + 0x7fffu + ((x >> 16) & 1u)) >> 16);   // RNE
}
static __device__ __forceinline__ float bf2f(unsigned short h) {
    return __uint_as_float(((unsigned int)h) << 16);
}

// async 16B global->LDS (wave-uniform LDS base + lane*16)
static __device__ __forceinline__ void gload_lds16(const void* g, void* s) {
    __builtin_amdgcn_global_load_lds((const __attribute__((address_space(1))) void*)g,
                                     (__attribute__((address_space(3))) void*)s, 16, 0, 0);
}

// ---------------- zero rowsum ----------------
__global__ void zero_kernel(float* __restrict__ p, int n) {
    int i = blockIdx.x * blockDim.x + threadIdx.x;
    if (i < n) p[i] = 0.f;
}

// ---------------- prep: dec_out fp32 -> bf16 (vectorized x4) ----------------
__global__ void convert_a_kernel(const float* __restrict__ A, unsigned short* __restrict__ Abf, int n4) {
    int i = blockIdx.x * blockDim.x + threadIdx.x;
    if (i < n4) {
        float4 f = ((const float4*)A)[i];
        short4v s;
        s[0] = (short)f2bf(f.x); s[1] = (short)f2bf(f.y);
        s[2] = (short)f2bf(f.z); s[3] = (short)f2bf(f.w);
        *(short4v*)(Abf + i * 4) = s;
    }
}

// ---------------- prep: W (512 x 32000) fp32 -> WT (32000 x 512) bf16 ----------------
// 64x64 tile, float4 loads (16B/lane), short8 stores (16B/lane). 65-pad LDS:
// write phase reads tile[c*8+j][v] -> bank (8c+v+j)&31, 2-way only (free).
__global__ __launch_bounds__(256) void transpose_kernel(const float* __restrict__ W,
                                                        unsigned short* __restrict__ WT) {
    __shared__ float tile[64][65];
    const int k0 = blockIdx.y * 64;
    const int v0 = blockIdx.x * 64;
    const int t  = threadIdx.x;
    const int tx = t & 15;            // float4 col within tile row
    const int ty = t >> 4;            // 0..15
#pragma unroll
    for (int i = 0; i < 64; i += 16) {
        float4 f = *(const float4*)&W[(size_t)(k0 + ty + i) * Vdim + v0 + tx * 4];
        tile[ty + i][tx * 4 + 0] = f.x;
        tile[ty + i][tx * 4 + 1] = f.y;
        tile[ty + i][tx * 4 + 2] = f.z;
        tile[ty + i][tx * 4 + 3] = f.w;
    }
    __syncthreads();
    const int c = t & 7;              // k-chunk of 8
    const int v = t >> 3;             // 0..31
#pragma unroll
    for (int i = 0; i < 64; i += 32) {
        short8 s;
#pragma unroll
        for (int j = 0; j < 8; ++j) s[j] = (short)f2bf(tile[c * 8 + j][v + i]);
        *(short8*)&WT[(size_t)(v0 + v + i) * Hdim + k0 + c * 8] = s;
    }
}

// ---------------- GEMM: logits(800x32000) = Abf * WT^T + bias; bf16 store + row sumexp ----
// 128x128 tile, 4 waves, BK=64. Changes vs prior version:
//  (1) double-buffered LDS + prefetch: stage K-tile t+1 BEFORE computing t; single
//      __syncthreads() per K-step (its vmcnt(0) drain = the 2-phase template's drain point).
//      Memory stays in flight during the ds_read+MFMA phase instead of idling.
//  (2) 1D grid + bijective XCD swizzle (nwg=1750): each XCD owns a contiguous n-range,
//      m-fastest, so the 7 m-blocks sharing a B-tile hit the same per-XCD L2.
__global__ __launch_bounds__(256) void gemm_kernel(const unsigned short* __restrict__ Abf,
                                                   const unsigned short* __restrict__ WT,
                                                   const float* __restrict__ bias,
                                                   unsigned short* __restrict__ logitsbf,
                                                   float* __restrict__ rowsum) {
    __shared__ __align__(16) unsigned short As[2 * 128 * 64];   // 2 x 16 KB
    __shared__ __align__(16) unsigned short Bs[2 * 128 * 64];   // 2 x 16 KB

    const int tid  = threadIdx.x;
    const int lane = tid & 63;
    const int wave = tid >> 6;
    const int l15  = lane & 15;
    const int kq   = lane >> 4;            // 0..3

    // bijective XCD swizzle (m204): xcd = orig%8 gets contiguous wg-range
    const int NWG = 7 * 250;               // 1750
    const int orig = blockIdx.x;
    const int xcd = orig & 7;
    const int q8  = NWG >> 3;              // 218
    const int r8  = NWG & 7;               // 6
    const int wg  = (xcd < r8 ? xcd * (q8 + 1) : r8 * (q8 + 1) + (xcd - r8) * q8) + (orig >> 3);
    const int m_blk = (wg % 7) * 128;      // m-fastest: B-tile reuse is L2-local
    const int n_blk = (wg / 7) * 128;

    const int wm = wave & 1, wn = wave >> 1;
    const int m0 = wm * 64, n0 = wn * 64;

    // staging: 1024 16B-chunks per matrix; chunk = (q*4+wave)*64 + lane
    const unsigned short* agp[4];
    const unsigned short* bgp[4];
    int lslot[4];
#pragma unroll
    for (int q = 0; q < 4; ++q) {
        int chunk = (q * 4 + wave) * 64 + lane;
        int row = chunk >> 3, c = chunk & 7;
        int gc  = c ^ (row & 7);                 // XOR swizzle: lane fetches the chunk that
        int arow = m_blk + row;                  // belongs at its contiguous LDS slot
        if (arow >= Mdim) arow = Mdim - 1;       // clamp; epilogue masks
        agp[q] = Abf + (size_t)arow * Hdim + gc * 8;
        bgp[q] = WT + (size_t)(n_blk + row) * Hdim + gc * 8;
        lslot[q] = (q * 4 + wave) * 512;         // wave-uniform base (shorts)
    }

    // fragment LDS offsets (shorts): row*64 + ((ks*4+kq)^(row&7))*8
    int a_off[2][4], b_off[2][4];
#pragma unroll
    for (int ks = 0; ks < 2; ++ks)
#pragma unroll
        for (int i = 0; i < 4; ++i) {
            int ra = m0 + i * 16 + l15;
            a_off[ks][i] = ra * 64 + (((ks * 4 + kq) ^ (ra & 7)) * 8);
            int rb = n0 + i * 16 + l15;
            b_off[ks][i] = rb * 64 + (((ks * 4 + kq) ^ (rb & 7)) * 8);
        }

    float4_t acc[4][4] = {};

    // prologue: stage K-tile 0 into buffer 0
#pragma unroll
    for (int q = 0; q < 4; ++q) {
        gload_lds16(agp[q], As + lslot[q]);
        gload_lds16(bgp[q], Bs + lslot[q]);
    }
    __syncthreads();

    int cur = 0;
#pragma unroll
    for (int kt = 0; kt < 8; ++kt) {
        // prefetch next K-tile into the other buffer (in flight during compute)
        if (kt < 7) {
            const int ko = (kt + 1) * 64;
            const int nb = (cur ^ 1) * 8192;
#pragma unroll
            for (int q = 0; q < 4; ++q) {
                gload_lds16(agp[q] + ko, As + nb + lslot[q]);
                gload_lds16(bgp[q] + ko, Bs + nb + lslot[q]);
            }
        }
        const unsigned short* Ab = As + cur * 8192;
        const unsigned short* Bb = Bs + cur * 8192;
#pragma unroll
        for (int ks = 0; ks < 2; ++ks) {
            short8 af[4], bfr[4];
#pragma unroll
            for (int i = 0; i < 4; ++i) af[i]  = *(const short8*)(Ab + a_off[ks][i]);
#pragma unroll
            for (int j = 0; j < 4; ++j) bfr[j] = *(const short8*)(Bb + b_off[ks][j]);
#pragma unroll
            for (int i = 0; i < 4; ++i)
#pragma unroll
                for (int j = 0; j < 4; ++j)
                    acc[i][j] = __builtin_amdgcn_mfma_f32_16x16x32_bf16(af[i], bfr[j], acc[i][j], 0, 0, 0);
        }
        if (kt < 7) {
            __syncthreads();     // drains prefetch (vmcnt 0) + lgkm; buffers safe to swap
            cur ^= 1;
        }
    }

    // epilogue: bias add, bf16 store, per-row partial sum of exp -> atomicAdd rowsum
    float bj[4];
#pragma unroll
    for (int j = 0; j < 4; ++j) bj[j] = bias[n_blk + n0 + j * 16 + l15];

#pragma unroll
    for (int i = 0; i < 4; ++i) {
        float se[4] = {0.f, 0.f, 0.f, 0.f};
        int grow0 = m_blk + m0 + i * 16 + kq * 4;      // + r
#pragma unroll
        for (int j = 0; j < 4; ++j) {
            int col = n_blk + n0 + j * 16 + l15;
#pragma unroll
            for (int r = 0; r < 4; ++r) {
                float v = acc[i][j][r] + bj[j];
                se[r] += __expf(v);
                if (grow0 + r < Mdim)
                    logitsbf[(size_t)(grow0 + r) * Vdim + col] = f2bf(v);
            }
        }
#pragma unroll
        for (int r = 0; r < 4; ++r) {
#pragma unroll
            for (int off = 8; off; off >>= 1)
                se[r] += __shfl_xor(se[r], off, 64);   // reduce over the 16 cols (l15)
        }
        if (l15 == 0) {
#pragma unroll
            for (int r = 0; r < 4; ++r)
                if (grow0 + r < Mdim) atomicAdd(&rowsum[grow0 + r], se[r]);
        }
    }
}

// ---------------- combine: sparse copy-dist scatter + log blend (single logits pass) ----
__global__ __launch_bounds__(512) void combine_kernel(const unsigned short* __restrict__ logitsbf,
                                                      const float* __restrict__ weights,
                                                      const float* __restrict__ p_trans,
                                                      const float* __restrict__ trans_probs,
                                                      const float* __restrict__ probs,
                                                      const int* __restrict__ idxes,
                                                      const float* __restrict__ rowsum,
                                                      float* __restrict__ out) {
    __shared__ __align__(16) float ts[VHALF];

    int bt = blockIdx.x;           // 0..799
    int b  = bt / Tdim;
    int tid = threadIdx.x;

    float pt = p_trans[bt];
    float c1 = (1.f - pt) / rowsum[bt];

    const short8* lrow8 = (const short8*)(logitsbf + (size_t)bt * Vdim);
    float4* out4 = (float4*)(out + (size_t)bt * Vdim);
    float4* ts4  = (float4*)ts;

    for (int h = 0; h < 2; ++h) {
        float4 z = make_float4(0.f, 0.f, 0.f, 0.f);
        for (int i = tid; i < VHALF / 4; i += 512) ts4[i] = z;
        __syncthreads();

        for (int i = tid; i < Sdim * Kk; i += 512) {
            float pv  = probs[b * (Sdim * Kk) + i];
            float tpv = trans_probs[b * (Sdim * Kk) + i];
            int   idx = idxes[b * (Sdim * Kk) + i];
            int   rel = idx - h * VHALF;
            if (pv > 0.05f && (unsigned)rel < (unsigned)VHALF) {
                float w = weights[bt * Sdim + (i >> 3)];
                atomicAdd(&ts[rel], w * tpv);
            }
        }
        __syncthreads();

        for (int i = tid; i < VHALF / 8; i += 512) {
            short8 x8 = lrow8[h * (VHALF / 8) + i];
            float4 t0 = ts4[i * 2];
            float4 t1 = ts4[i * 2 + 1];
            float4 o0, o1;
            o0.x = __logf(pt * t0.x + c1 * __expf(bf2f((unsigned short)x8[0])));
            o0.y = __logf(pt * t0.y + c1 * __expf(bf2f((unsigned short)x8[1])));
            o0.z = __logf(pt * t0.z + c1 * __expf(bf2f((unsigned short)x8[2])));
            o0.w = __logf(pt * t0.w + c1 * __expf(bf2f((unsigned short)x8[3])));
            o1.x = __logf(pt * t1.x + c1 * __expf(bf2f((unsigned short)x8[4])));
            o1.y = __logf(pt * t1.y + c1 * __expf(bf2f((unsigned short)x8[5])));
            o1.z = __logf(pt * t1.z + c1 * __expf(bf2f((unsigned short)x8[6])));
            o1.w = __logf(pt * t1.w + c1 * __expf(bf2f((unsigned short)x8[7])));
            out4[(h * (VHALF / 8) + i) * 2]     = o0;
            out4[(h * (VHALF / 8) + i) * 2 + 1] = o1;
        }
        __syncthreads();
    }
}

extern "C" void kernel_launch(void* const* d_in, const int* in_sizes, int n_in,
                              void* d_out, int out_size, void* d_ws, size_t ws_size,
                              hipStream_t stream) {
    const float* dec_out     = (const float*)d_in[0];   // (8,100,512)
    const float* W           = (const float*)d_in[1];   // (512,32000)
    const float* bias        = (const float*)d_in[2];   // (32000,)
    const float* weights     = (const float*)d_in[3];   // (8,100,400)
    const float* p_trans     = (const float*)d_in[4];   // (8,100,1)
    const float* trans_probs = (const float*)d_in[5];   // (8,400,8)
    const float* probs       = (const float*)d_in[6];   // (8,400,8)
    const int*   idxes       = (const int*)d_in[7];     // (8,400,8)
    float* out = (float*)d_out;

    char* wsb = (char*)d_ws;
    unsigned short* Abf      = (unsigned short*)wsb;                      // 819,200 B
    unsigned short* WT       = (unsigned short*)(wsb + (1ull << 20));     // 32.8 MB
    unsigned short* logitsbf = (unsigned short*)(wsb + (35ull << 20));    // 51.2 MB
    float*          rowsum   = (float*)(wsb + (90ull << 20));             // 3200 B

    zero_kernel<<<dim3(4), dim3(256), 0, stream>>>(rowsum, Mdim);
    convert_a_kernel<<<dim3((Mdim * Hdim / 4 + 255) / 256), dim3(256), 0, stream>>>(dec_out, Abf, Mdim * Hdim / 4);
    transpose_kernel<<<dim3(Vdim / 64, Hdim / 64), dim3(256), 0, stream>>>(W, WT);
    gemm_kernel<<<dim3(7 * (Vdim / 128)), dim3(256), 0, stream>>>(Abf, WT, bias, logitsbf, rowsum);
    combine_kernel<<<dim3(Mdim), dim3(512), 0, stream>>>(logitsbf, weights, p_trans, trans_probs,
                                                         probs, idxes, rowsum, out);
}